// Round 1
// baseline (716.565 us; speedup 1.0000x reference)
//
#include <hip/hip_runtime.h>

#define N_NODES 30000
#define N_EDGES 240000
#define NF 32
#define EF 16
#define HF 64
#define NC 8

// wbuf layout (float offsets)
#define W_COMB 0      // [16][16] We @ Wem[64:128)
#define B_COMB 256    // [16]     bem + be@Wem[64:128)
#define W_NC   272    // [16][32] We @ Wnm[0:64)
#define B_VEC  784    // [32]     be @ Wnm[0:64)
#define W_SD   816    // [32][32] cols 0-15: Wn@Wem[0:64) ; cols 16-31: Wn@Wem[128:192)
#define W_NB   1840   // [32][32] Wn @ Wnm[64:128)
#define B_SD   2864   // [32]     [bn@WemS | bn@WemD]
#define B_NB   2896   // [32]     bnm + bn@Wnm[64:128)
#define W_NF   2928   // [32][8]  Wn @ Wfc
#define B_NF   3184   // [8]      bfc + bn@Wfc

__device__ __forceinline__ float sigmoidf_(float x) {
  return 1.0f / (1.0f + __expf(-x));
}

// ---------------------------------------------------------------------------
__global__ void __launch_bounds__(256) hist_kernel(
    const int* __restrict__ dst, int* __restrict__ cnt) {
  int e = blockIdx.x * 256 + threadIdx.x;
  if (e < N_EDGES) atomicAdd(&cnt[dst[e]], 1);
}

// exclusive scan of cnt[30000] -> off[30001], cursor = copy of off
__global__ void __launch_bounds__(1024) scan_kernel(
    const int* __restrict__ cnt, int* __restrict__ off, int* __restrict__ cursor) {
  __shared__ int part[1024];
  int t = threadIdx.x;
  const int CH = (N_NODES + 1023) / 1024;   // 30
  int base = t * CH;
  int lc[CH];
  int sum = 0;
  for (int i = 0; i < CH; ++i) {
    int idx = base + i;
    lc[i] = (idx < N_NODES) ? cnt[idx] : 0;
    sum += lc[i];
  }
  part[t] = sum;
  __syncthreads();
  for (int ofs = 1; ofs < 1024; ofs <<= 1) {
    int v = (t >= ofs) ? part[t - ofs] : 0;
    __syncthreads();
    part[t] += v;
    __syncthreads();
  }
  int run = (t == 0) ? 0 : part[t - 1];
  for (int i = 0; i < CH; ++i) {
    int idx = base + i;
    if (idx < N_NODES) {
      off[idx] = run;
      cursor[idx] = run;
      run += lc[i];
    }
  }
  if (t == 1023) off[N_NODES] = part[1023];
}

__global__ void __launch_bounds__(256) scatter_kernel(
    const float* __restrict__ edge_feat, const int* __restrict__ src,
    const int* __restrict__ dst, int* __restrict__ cursor,
    unsigned short* __restrict__ src_s, unsigned short* __restrict__ dst_s,
    float* __restrict__ e_buf) {
  int e = blockIdx.x * 256 + threadIdx.x;
  if (e >= N_EDGES) return;
  int d = dst[e];
  int pos = atomicAdd(&cursor[d], 1);
  src_s[pos] = (unsigned short)src[e];
  dst_s[pos] = (unsigned short)d;
  const float4* ep = (const float4*)(edge_feat + (size_t)e * EF);
  float4* op = (float4*)(e_buf + (size_t)pos * EF);
  op[0] = ep[0]; op[1] = ep[1]; op[2] = ep[2]; op[3] = ep[3];
}

// ---------------------------------------------------------------------------
__global__ void __launch_bounds__(256) precompute_kernel(
    const float* __restrict__ Wn, const float* __restrict__ bn,
    const float* __restrict__ We, const float* __restrict__ be,
    const float* __restrict__ Wem, const float* __restrict__ bem,
    const float* __restrict__ Wnm, const float* __restrict__ bnm,
    const float* __restrict__ Wfc, const float* __restrict__ bfc,
    float* __restrict__ wbuf) {
  int tid = threadIdx.x;
  {  // Wcomb
    int r = tid >> 4, c = tid & 15;
    float acc = 0.f;
    for (int j = 0; j < HF; ++j) acc = fmaf(We[r * HF + j], Wem[(HF + j) * EF + c], acc);
    wbuf[W_COMB + tid] = acc;
  }
  for (int idx = tid; idx < EF * NF; idx += 256) {  // Wnc
    int r = idx >> 5, c = idx & 31;
    float acc = 0.f;
    for (int j = 0; j < HF; ++j) acc = fmaf(We[r * HF + j], Wnm[j * NF + c], acc);
    wbuf[W_NC + idx] = acc;
  }
  for (int idx = tid; idx < NF * NF; idx += 256) {  // WSD
    int r = idx >> 5, c = idx & 31;
    float acc = 0.f;
    if (c < EF) {
      for (int j = 0; j < HF; ++j) acc = fmaf(Wn[r * HF + j], Wem[j * EF + c], acc);
    } else {
      int cc = c - EF;
      for (int j = 0; j < HF; ++j) acc = fmaf(Wn[r * HF + j], Wem[(2 * HF + j) * EF + cc], acc);
    }
    wbuf[W_SD + idx] = acc;
  }
  for (int idx = tid; idx < NF * NF; idx += 256) {  // WnB
    int r = idx >> 5, c = idx & 31;
    float acc = 0.f;
    for (int j = 0; j < HF; ++j) acc = fmaf(Wn[r * HF + j], Wnm[(HF + j) * NF + c], acc);
    wbuf[W_NB + idx] = acc;
  }
  if (tid < NF * NC) {  // Wnf
    int r = tid >> 3, c = tid & 7;
    float acc = 0.f;
    for (int j = 0; j < HF; ++j) acc = fmaf(Wn[r * HF + j], Wfc[j * NC + c], acc);
    wbuf[W_NF + tid] = acc;
  }
  if (tid < EF) {  // bcomb
    float acc = bem[tid];
    for (int j = 0; j < HF; ++j) acc = fmaf(be[j], Wem[(HF + j) * EF + tid], acc);
    wbuf[B_COMB + tid] = acc;
  }
  if (tid < NF) {  // bvec
    float acc = 0.f;
    for (int j = 0; j < HF; ++j) acc = fmaf(be[j], Wnm[j * NF + tid], acc);
    wbuf[B_VEC + tid] = acc;
  }
  if (tid < NF) {  // bSD
    float acc = 0.f;
    if (tid < EF) {
      for (int j = 0; j < HF; ++j) acc = fmaf(bn[j], Wem[j * EF + tid], acc);
    } else {
      int cc = tid - EF;
      for (int j = 0; j < HF; ++j) acc = fmaf(bn[j], Wem[(2 * HF + j) * EF + cc], acc);
    }
    wbuf[B_SD + tid] = acc;
  }
  if (tid < NF) {  // bNB
    float acc = bnm[tid];
    for (int j = 0; j < HF; ++j) acc = fmaf(bn[j], Wnm[(HF + j) * NF + tid], acc);
    wbuf[B_NB + tid] = acc;
  }
  if (tid < NC) {  // bnf
    float acc = bfc[tid];
    for (int j = 0; j < HF; ++j) acc = fmaf(bn[j], Wfc[j * NC + tid], acc);
    wbuf[B_NF + tid] = acc;
  }
}

// ---------------------------------------------------------------------------
// 4 threads per node, p = gid&3.
// Projection output split: p0 -> Ps (WSD cols 0-15), p1 -> Pd (WSD cols 16-31),
//                          p2 -> hpart[0:16) (WnB cols 0-15), p3 -> hpart[16:32).
// wbase = sPRJ + (p>>1)*1024 + (p&1)*16 ; bias = sPB + p*16.
// ---------------------------------------------------------------------------

// init: [Ps|Pd] = x@WSD + bSD ; hpart = x@WnB + bNB  (no sigmoid)
__global__ void __launch_bounds__(256) init_proj_kernel(
    const float* __restrict__ node_feat, const float* __restrict__ wbuf,
    float* __restrict__ Ps, float* __restrict__ Pd, float* __restrict__ hpart) {
  __shared__ float sPRJ[2048];
  __shared__ float sPB[64];
  for (int i = threadIdx.x; i < 2048; i += 256) sPRJ[i] = wbuf[W_SD + i];
  if (threadIdx.x < 64) sPB[threadIdx.x] = wbuf[B_SD + threadIdx.x];
  __syncthreads();
  int gid = blockIdx.x * 256 + threadIdx.x;
  int n = gid >> 2, p = gid & 3;
  if (n >= N_NODES) return;
  float x[NF];
  const float4* xp = (const float4*)(node_feat + (size_t)n * NF);
#pragma unroll
  for (int k4 = 0; k4 < 8; ++k4) {
    float4 v = xp[k4];
    x[4 * k4] = v.x; x[4 * k4 + 1] = v.y; x[4 * k4 + 2] = v.z; x[4 * k4 + 3] = v.w;
  }
  float pr[16];
  const float* pb = sPB + p * 16;
#pragma unroll
  for (int j = 0; j < 16; ++j) pr[j] = pb[j];
  const float* wbase = sPRJ + (p >> 1) * 1024 + (p & 1) * 16;
  for (int k = 0; k < NF; ++k) {
    float v = x[k];
    const float4* wr = (const float4*)(wbase + k * NF);
#pragma unroll
    for (int j4 = 0; j4 < 4; ++j4) {
      float4 w = wr[j4];
      pr[4 * j4 + 0] = fmaf(v, w.x, pr[4 * j4 + 0]);
      pr[4 * j4 + 1] = fmaf(v, w.y, pr[4 * j4 + 1]);
      pr[4 * j4 + 2] = fmaf(v, w.z, pr[4 * j4 + 2]);
      pr[4 * j4 + 3] = fmaf(v, w.w, pr[4 * j4 + 3]);
    }
  }
  float* dst0;
  if (p == 0)      dst0 = Ps + (size_t)n * EF;
  else if (p == 1) dst0 = Pd + (size_t)n * EF;
  else             dst0 = hpart + (size_t)n * NF + (size_t)(p & 1) * 16;
  float4* o = (float4*)dst0;
#pragma unroll
  for (int j4 = 0; j4 < 4; ++j4)
    o[j4] = make_float4(pr[4 * j4], pr[4 * j4 + 1], pr[4 * j4 + 2], pr[4 * j4 + 3]);
}

// ---------------------------------------------------------------------------
// node pass i (1..11): z = hpart + deg*bvec + segsum(e)@Wnc ; sig = sigmoid(z)
// then emit next-iter projections: [Ps|Pd] = sig@WSD+bSD ; hpart' = sig@WnB+bNB
// 4 threads/node: lane p sums float4 quarter of each edge row (4-lane group
// reads a full contiguous 64B e_buf row); edge loop unrolled x4 to break the
// load-latency chain; z assembled via xor-1/xor-2 butterfly.
// ---------------------------------------------------------------------------
__global__ void __launch_bounds__(256) node_kernel(
    const float* __restrict__ e_buf, float* __restrict__ hpart,
    const int* __restrict__ off, const float* __restrict__ wbuf,
    float* __restrict__ Ps_next, float* __restrict__ Pd_next) {
  __shared__ float sWnc[EF * 36];   // padded stride 36 (4-way -> free 2-way)
  __shared__ float sbvec[NF];
  __shared__ float sPRJ[2048];
  __shared__ float sPB[64];
  for (int i = threadIdx.x; i < 2048; i += 256) sPRJ[i] = wbuf[W_SD + i];
  for (int i = threadIdx.x; i < EF * NF; i += 256)
    sWnc[(i >> 5) * 36 + (i & 31)] = wbuf[W_NC + i];
  if (threadIdx.x < 64) sPB[threadIdx.x] = wbuf[B_SD + threadIdx.x];
  if (threadIdx.x < NF) sbvec[threadIdx.x] = wbuf[B_VEC + threadIdx.x];
  __syncthreads();
  int gid = blockIdx.x * 256 + threadIdx.x;
  int n = gid >> 2, p = gid & 3;
  if (n >= N_NODES) return;
  int o0 = off[n], o1 = off[n + 1];

  // prefetch hpart early (p==0 only; overlaps edge loop)
  float4 hv[8];
  if (p == 0) {
    const float4* hp = (const float4*)(hpart + (size_t)n * NF);
#pragma unroll
    for (int j4 = 0; j4 < 8; ++j4) hv[j4] = hp[j4];
  }

  // edge quarter-sum, unrolled x4 (independent loads)
  float4 sA = make_float4(0.f, 0.f, 0.f, 0.f);
  float4 sB = make_float4(0.f, 0.f, 0.f, 0.f);
  const float* ebase = e_buf + 4 * p;
  int q = o0;
  for (; q + 3 < o1; q += 4) {
    float4 a = *(const float4*)(ebase + (size_t)q * EF);
    float4 b = *(const float4*)(ebase + (size_t)(q + 1) * EF);
    float4 c = *(const float4*)(ebase + (size_t)(q + 2) * EF);
    float4 d = *(const float4*)(ebase + (size_t)(q + 3) * EF);
    sA.x += a.x; sA.y += a.y; sA.z += a.z; sA.w += a.w;
    sB.x += b.x; sB.y += b.y; sB.z += b.z; sB.w += b.w;
    sA.x += c.x; sA.y += c.y; sA.z += c.z; sA.w += c.w;
    sB.x += d.x; sB.y += d.y; sB.z += d.z; sB.w += d.w;
  }
  for (; q < o1; ++q) {
    float4 a = *(const float4*)(ebase + (size_t)q * EF);
    sA.x += a.x; sA.y += a.y; sA.z += a.z; sA.w += a.w;
  }
  float s4[4] = {sA.x + sB.x, sA.y + sB.y, sA.z + sB.z, sA.w + sB.w};

  float z[NF];
  if (p == 0) {
#pragma unroll
    for (int j4 = 0; j4 < 8; ++j4) {
      z[4 * j4] = hv[j4].x; z[4 * j4 + 1] = hv[j4].y;
      z[4 * j4 + 2] = hv[j4].z; z[4 * j4 + 3] = hv[j4].w;
    }
  } else if (p == 1) {
    float dg = (float)(o1 - o0);
#pragma unroll
    for (int j = 0; j < NF; ++j) z[j] = dg * sbvec[j];
  } else {
#pragma unroll
    for (int j = 0; j < NF; ++j) z[j] = 0.f;
  }
#pragma unroll
  for (int kk = 0; kk < 4; ++kk) {
    float v = s4[kk];
    const float4* wr = (const float4*)(sWnc + (4 * p + kk) * 36);
#pragma unroll
    for (int j4 = 0; j4 < 8; ++j4) {
      float4 w = wr[j4];
      z[4 * j4 + 0] = fmaf(v, w.x, z[4 * j4 + 0]);
      z[4 * j4 + 1] = fmaf(v, w.y, z[4 * j4 + 1]);
      z[4 * j4 + 2] = fmaf(v, w.z, z[4 * j4 + 2]);
      z[4 * j4 + 3] = fmaf(v, w.w, z[4 * j4 + 3]);
    }
  }
#pragma unroll
  for (int j = 0; j < NF; ++j) z[j] += __shfl_xor(z[j], 1, 64);
#pragma unroll
  for (int j = 0; j < NF; ++j) z[j] += __shfl_xor(z[j], 2, 64);
#pragma unroll
  for (int j = 0; j < NF; ++j) z[j] = sigmoidf_(z[j]);

  float pr[16];
  const float* pb = sPB + p * 16;
#pragma unroll
  for (int j = 0; j < 16; ++j) pr[j] = pb[j];
  const float* wbase = sPRJ + (p >> 1) * 1024 + (p & 1) * 16;
  for (int k = 0; k < NF; ++k) {
    float v = z[k];
    const float4* wr = (const float4*)(wbase + k * NF);
#pragma unroll
    for (int j4 = 0; j4 < 4; ++j4) {
      float4 w = wr[j4];
      pr[4 * j4 + 0] = fmaf(v, w.x, pr[4 * j4 + 0]);
      pr[4 * j4 + 1] = fmaf(v, w.y, pr[4 * j4 + 1]);
      pr[4 * j4 + 2] = fmaf(v, w.z, pr[4 * j4 + 2]);
      pr[4 * j4 + 3] = fmaf(v, w.w, pr[4 * j4 + 3]);
    }
  }
  float* dst0;
  if (p == 0)      dst0 = Ps_next + (size_t)n * EF;
  else if (p == 1) dst0 = Pd_next + (size_t)n * EF;
  else             dst0 = hpart + (size_t)n * NF + (size_t)(p & 1) * 16;
  float4* o = (float4*)dst0;
#pragma unroll
  for (int j4 = 0; j4 < 4; ++j4)
    o[j4] = make_float4(pr[4 * j4], pr[4 * j4 + 1], pr[4 * j4 + 2], pr[4 * j4 + 3]);
}

// ---------------------------------------------------------------------------
// final node pass (iter 12): z/sig as above, then out = sig @ Wnf + bnf
// ---------------------------------------------------------------------------
__global__ void __launch_bounds__(256) final_kernel(
    const float* __restrict__ e_buf, const float* __restrict__ hpart,
    const int* __restrict__ off, const float* __restrict__ wbuf,
    float* __restrict__ out) {
  __shared__ float sWnc[EF * 36];
  __shared__ float sbvec[NF];
  __shared__ float sWNF[NF * NC];
  __shared__ float sBNF[NC];
  for (int i = threadIdx.x; i < EF * NF; i += 256)
    sWnc[(i >> 5) * 36 + (i & 31)] = wbuf[W_NC + i];
  if (threadIdx.x < NF) sbvec[threadIdx.x] = wbuf[B_VEC + threadIdx.x];
  if (threadIdx.x < NF * NC) sWNF[threadIdx.x] = wbuf[W_NF + threadIdx.x];
  if (threadIdx.x < NC) sBNF[threadIdx.x] = wbuf[B_NF + threadIdx.x];
  __syncthreads();
  int gid = blockIdx.x * 256 + threadIdx.x;
  int n = gid >> 2, p = gid & 3;
  if (n >= N_NODES) return;
  int o0 = off[n], o1 = off[n + 1];

  float4 hv[8];
  if (p == 0) {
    const float4* hp = (const float4*)(hpart + (size_t)n * NF);
#pragma unroll
    for (int j4 = 0; j4 < 8; ++j4) hv[j4] = hp[j4];
  }

  float4 sA = make_float4(0.f, 0.f, 0.f, 0.f);
  float4 sB = make_float4(0.f, 0.f, 0.f, 0.f);
  const float* ebase = e_buf + 4 * p;
  int q = o0;
  for (; q + 3 < o1; q += 4) {
    float4 a = *(const float4*)(ebase + (size_t)q * EF);
    float4 b = *(const float4*)(ebase + (size_t)(q + 1) * EF);
    float4 c = *(const float4*)(ebase + (size_t)(q + 2) * EF);
    float4 d = *(const float4*)(ebase + (size_t)(q + 3) * EF);
    sA.x += a.x; sA.y += a.y; sA.z += a.z; sA.w += a.w;
    sB.x += b.x; sB.y += b.y; sB.z += b.z; sB.w += b.w;
    sA.x += c.x; sA.y += c.y; sA.z += c.z; sA.w += c.w;
    sB.x += d.x; sB.y += d.y; sB.z += d.z; sB.w += d.w;
  }
  for (; q < o1; ++q) {
    float4 a = *(const float4*)(ebase + (size_t)q * EF);
    sA.x += a.x; sA.y += a.y; sA.z += a.z; sA.w += a.w;
  }
  float s4[4] = {sA.x + sB.x, sA.y + sB.y, sA.z + sB.z, sA.w + sB.w};

  float z[NF];
  if (p == 0) {
#pragma unroll
    for (int j4 = 0; j4 < 8; ++j4) {
      z[4 * j4] = hv[j4].x; z[4 * j4 + 1] = hv[j4].y;
      z[4 * j4 + 2] = hv[j4].z; z[4 * j4 + 3] = hv[j4].w;
    }
  } else if (p == 1) {
    float dg = (float)(o1 - o0);
#pragma unroll
    for (int j = 0; j < NF; ++j) z[j] = dg * sbvec[j];
  } else {
#pragma unroll
    for (int j = 0; j < NF; ++j) z[j] = 0.f;
  }
#pragma unroll
  for (int kk = 0; kk < 4; ++kk) {
    float v = s4[kk];
    const float4* wr = (const float4*)(sWnc + (4 * p + kk) * 36);
#pragma unroll
    for (int j4 = 0; j4 < 8; ++j4) {
      float4 w = wr[j4];
      z[4 * j4 + 0] = fmaf(v, w.x, z[4 * j4 + 0]);
      z[4 * j4 + 1] = fmaf(v, w.y, z[4 * j4 + 1]);
      z[4 * j4 + 2] = fmaf(v, w.z, z[4 * j4 + 2]);
      z[4 * j4 + 3] = fmaf(v, w.w, z[4 * j4 + 3]);
    }
  }
#pragma unroll
  for (int j = 0; j < NF; ++j) z[j] += __shfl_xor(z[j], 1, 64);
#pragma unroll
  for (int j = 0; j < NF; ++j) z[j] += __shfl_xor(z[j], 2, 64);
#pragma unroll
  for (int j = 0; j < NF; ++j) z[j] = sigmoidf_(z[j]);

  float o[NC];
#pragma unroll
  for (int c = 0; c < NC; ++c) o[c] = (p == 0) ? sBNF[c] : 0.f;
#pragma unroll
  for (int kk = 0; kk < 8; ++kk) {
    int k = 8 * p + kk;
    float v = z[k];
    const float* wr = sWNF + k * NC;
#pragma unroll
    for (int c = 0; c < NC; ++c) o[c] = fmaf(v, wr[c], o[c]);
  }
#pragma unroll
  for (int c = 0; c < NC; ++c) o[c] += __shfl_xor(o[c], 1, 64);
#pragma unroll
  for (int c = 0; c < NC; ++c) o[c] += __shfl_xor(o[c], 2, 64);
  if (p == 0) {
    float4* op = (float4*)(out + (size_t)n * NC);
    op[0] = make_float4(o[0], o[1], o[2], o[3]);
    op[1] = make_float4(o[4], o[5], o[6], o[7]);
  }
}

// ---------------------------------------------------------------------------
// edge pass i (1..11), sorted order, in-place on e_buf:
//   z = bcomb + e@Wcomb + Ps[src] + Pd[dst] ; e' = sigmoid(z)
// ---------------------------------------------------------------------------
__global__ void __launch_bounds__(256) edge_kernel(
    float* __restrict__ e_buf, const unsigned short* __restrict__ src_s,
    const unsigned short* __restrict__ dst_s,
    const float* __restrict__ Ps, const float* __restrict__ Pd,
    const float* __restrict__ wbuf) {
  __shared__ float sWC[EF * EF];
  __shared__ float sBC[EF];
  sWC[threadIdx.x] = wbuf[W_COMB + threadIdx.x];
  if (threadIdx.x < EF) sBC[threadIdx.x] = wbuf[B_COMB + threadIdx.x];
  __syncthreads();
  int q = blockIdx.x * 256 + threadIdx.x;
  if (q >= N_EDGES) return;
  int s = src_s[q], d = dst_s[q];

  float e[EF];
  float4* ebp = (float4*)(e_buf + (size_t)q * EF);
#pragma unroll
  for (int k4 = 0; k4 < 4; ++k4) {
    float4 v = ebp[k4];
    e[4 * k4] = v.x; e[4 * k4 + 1] = v.y; e[4 * k4 + 2] = v.z; e[4 * k4 + 3] = v.w;
  }
  const float4* ps = (const float4*)(Ps + (size_t)s * EF);
  const float4* pd = (const float4*)(Pd + (size_t)d * EF);
  float z[EF];
#pragma unroll
  for (int i4 = 0; i4 < 4; ++i4) {
    float4 a = ps[i4], b = pd[i4];
    z[4 * i4 + 0] = sBC[4 * i4 + 0] + a.x + b.x;
    z[4 * i4 + 1] = sBC[4 * i4 + 1] + a.y + b.y;
    z[4 * i4 + 2] = sBC[4 * i4 + 2] + a.z + b.z;
    z[4 * i4 + 3] = sBC[4 * i4 + 3] + a.w + b.w;
  }
#pragma unroll
  for (int k = 0; k < EF; ++k) {
    float v = e[k];
    const float4* wr = (const float4*)(sWC + k * EF);
#pragma unroll
    for (int i4 = 0; i4 < 4; ++i4) {
      float4 w = wr[i4];
      z[4 * i4 + 0] = fmaf(v, w.x, z[4 * i4 + 0]);
      z[4 * i4 + 1] = fmaf(v, w.y, z[4 * i4 + 1]);
      z[4 * i4 + 2] = fmaf(v, w.z, z[4 * i4 + 2]);
      z[4 * i4 + 3] = fmaf(v, w.w, z[4 * i4 + 3]);
    }
  }
#pragma unroll
  for (int i = 0; i < EF; ++i) z[i] = sigmoidf_(z[i]);
#pragma unroll
  for (int i4 = 0; i4 < 4; ++i4)
    ebp[i4] = make_float4(z[4 * i4], z[4 * i4 + 1], z[4 * i4 + 2], z[4 * i4 + 3]);
}

// ---------------------------------------------------------------------------
extern "C" void kernel_launch(void* const* d_in, const int* in_sizes, int n_in,
                              void* d_out, int out_size, void* d_ws, size_t ws_size,
                              hipStream_t stream) {
  const float* node_feat = (const float*)d_in[0];
  const float* edge_feat = (const float*)d_in[1];
  const int*   src = (const int*)d_in[2];
  const int*   dst = (const int*)d_in[3];
  const float* Wn  = (const float*)d_in[4];
  const float* bn  = (const float*)d_in[5];
  const float* We  = (const float*)d_in[6];
  const float* be  = (const float*)d_in[7];
  const float* Wem = (const float*)d_in[8];
  const float* bem = (const float*)d_in[9];
  const float* Wnm = (const float*)d_in[10];
  const float* bnm = (const float*)d_in[11];
  const float* Wfc = (const float*)d_in[12];
  const float* bfc = (const float*)d_in[13];
  float* out = (float*)d_out;

  float* ws    = (float*)d_ws;
  float* e_buf = ws;                                   // 3,840,000 f
  float* hpart = e_buf + (size_t)N_EDGES * EF;         //   960,000 f
  float* Ps0   = hpart + (size_t)N_NODES * NF;         //   480,000 f
  float* Pd0   = Ps0 + (size_t)N_NODES * EF;
  float* Ps1   = Pd0 + (size_t)N_NODES * EF;
  float* Pd1   = Ps1 + (size_t)N_NODES * EF;
  float* wbuf  = Pd1 + (size_t)N_NODES * EF;           //     4,096 f (3192 used)
  int* cnt     = (int*)(wbuf + 4096);                  //    30,000 i
  int* off     = cnt + N_NODES;                        //    30,001 i
  int* cursor  = off + N_NODES + 1;                    //    30,000 i
  unsigned short* src_s = (unsigned short*)(cursor + N_NODES);  // 240,000 u16
  unsigned short* dst_s = src_s + N_EDGES;                      // 240,000 u16
  float* PsA[2] = {Ps0, Ps1};
  float* PdA[2] = {Pd0, Pd1};

  const int EB  = (N_EDGES + 255) / 256;       // 938
  const int NB4 = (4 * N_NODES + 255) / 256;   // 469

  // --- counting sort of edges by dst (amortized over all 11 edge passes) ---
  hipMemsetAsync(cnt, 0, (size_t)N_NODES * sizeof(int), stream);
  hist_kernel<<<EB, 256, 0, stream>>>(dst, cnt);
  scan_kernel<<<1, 1024, 0, stream>>>(cnt, off, cursor);
  scatter_kernel<<<EB, 256, 0, stream>>>(edge_feat, src, dst, cursor,
                                         src_s, dst_s, e_buf);
  // --- fold all weight products on-device ---
  precompute_kernel<<<1, 256, 0, stream>>>(Wn, bn, We, be, Wem, bem,
                                           Wnm, bnm, Wfc, bfc, wbuf);
  // P_1 / hpart_1 from node_feat
  init_proj_kernel<<<NB4, 256, 0, stream>>>(node_feat, wbuf, Ps1, Pd1, hpart);

  // 13 reference iterations reduce to 11 edge + 12 node passes.
  // Order per iteration: node_i first (reads e-state i before edge_i
  // overwrites it in place); P ping-pong: edge_i reads P[i&1], node_i
  // writes P[(i+1)&1]; hpart updated in place by node_i.
  for (int i = 1; i <= 11; ++i) {
    node_kernel<<<NB4, 256, 0, stream>>>(e_buf, hpart, off, wbuf,
                                         PsA[(i + 1) & 1], PdA[(i + 1) & 1]);
    edge_kernel<<<EB, 256, 0, stream>>>(e_buf, src_s, dst_s,
                                        PsA[i & 1], PdA[i & 1], wbuf);
  }
  // node pass 12 fused with the output head (Wn@Wfc folded)
  final_kernel<<<NB4, 256, 0, stream>>>(e_buf, hpart, off, wbuf, out);
}

// Round 2
// 553.114 us; speedup vs baseline: 1.2955x; 1.2955x over previous
//
#include <hip/hip_runtime.h>

#define N_NODES 30000
#define N_EDGES 240000
#define NF 32
#define EF 16
#define HF 64
#define NC 8

#define EB_GRID  938   // (N_EDGES + 255) / 256
#define NB2_GRID 235   // (2*N_NODES + 255) / 256

// wbuf layout (float offsets)
#define W_COMB 0      // [16][16] We @ Wem[64:128)
#define B_COMB 256    // [16]     bem + be@Wem[64:128)
#define W_NC   272    // [16][32] We @ Wnm[0:64)
#define B_VEC  784    // [32]     be @ Wnm[0:64)
#define W_SD   816    // [32][32] cols 0-15: Wn@Wem[0:64) ; cols 16-31: Wn@Wem[128:192)
#define W_NB   1840   // [32][32] Wn @ Wnm[64:128)
#define B_SD   2864   // [32]     [bn@WemS | bn@WemD]
#define B_NB   2896   // [32]     bnm + bn@Wnm[64:128)
#define W_NF   2928   // [32][8]  Wn @ Wfc
#define B_NF   3184   // [8]      bfc + bn@Wfc

__device__ __forceinline__ float sigmoidf_(float x) {
  return 1.0f / (1.0f + __expf(-x));
}

// ---------------------------------------------------------------------------
// hist (blocks 0..EB-1) + precompute (block EB) fused — independent work.
// ---------------------------------------------------------------------------
__global__ void __launch_bounds__(256) hist_pre_kernel(
    const int* __restrict__ dst, int* __restrict__ cnt,
    const float* __restrict__ Wn, const float* __restrict__ bn,
    const float* __restrict__ We, const float* __restrict__ be,
    const float* __restrict__ Wem, const float* __restrict__ bem,
    const float* __restrict__ Wnm, const float* __restrict__ bnm,
    const float* __restrict__ Wfc, const float* __restrict__ bfc,
    float* __restrict__ wbuf) {
  if (blockIdx.x < EB_GRID) {
    int e = blockIdx.x * 256 + threadIdx.x;
    if (e < N_EDGES) atomicAdd(&cnt[dst[e]], 1);
    return;
  }
  int tid = threadIdx.x;
  {  // Wcomb
    int r = tid >> 4, c = tid & 15;
    float acc = 0.f;
    for (int j = 0; j < HF; ++j) acc = fmaf(We[r * HF + j], Wem[(HF + j) * EF + c], acc);
    wbuf[W_COMB + tid] = acc;
  }
  for (int idx = tid; idx < EF * NF; idx += 256) {  // Wnc
    int r = idx >> 5, c = idx & 31;
    float acc = 0.f;
    for (int j = 0; j < HF; ++j) acc = fmaf(We[r * HF + j], Wnm[j * NF + c], acc);
    wbuf[W_NC + idx] = acc;
  }
  for (int idx = tid; idx < NF * NF; idx += 256) {  // WSD
    int r = idx >> 5, c = idx & 31;
    float acc = 0.f;
    if (c < EF) {
      for (int j = 0; j < HF; ++j) acc = fmaf(Wn[r * HF + j], Wem[j * EF + c], acc);
    } else {
      int cc = c - EF;
      for (int j = 0; j < HF; ++j) acc = fmaf(Wn[r * HF + j], Wem[(2 * HF + j) * EF + cc], acc);
    }
    wbuf[W_SD + idx] = acc;
  }
  for (int idx = tid; idx < NF * NF; idx += 256) {  // WnB
    int r = idx >> 5, c = idx & 31;
    float acc = 0.f;
    for (int j = 0; j < HF; ++j) acc = fmaf(Wn[r * HF + j], Wnm[(HF + j) * NF + c], acc);
    wbuf[W_NB + idx] = acc;
  }
  if (tid < NF * NC) {  // Wnf
    int r = tid >> 3, c = tid & 7;
    float acc = 0.f;
    for (int j = 0; j < HF; ++j) acc = fmaf(Wn[r * HF + j], Wfc[j * NC + c], acc);
    wbuf[W_NF + tid] = acc;
  }
  if (tid < EF) {  // bcomb
    float acc = bem[tid];
    for (int j = 0; j < HF; ++j) acc = fmaf(be[j], Wem[(HF + j) * EF + tid], acc);
    wbuf[B_COMB + tid] = acc;
  }
  if (tid < NF) {  // bvec
    float acc = 0.f;
    for (int j = 0; j < HF; ++j) acc = fmaf(be[j], Wnm[j * NF + tid], acc);
    wbuf[B_VEC + tid] = acc;
  }
  if (tid < NF) {  // bSD
    float acc = 0.f;
    if (tid < EF) {
      for (int j = 0; j < HF; ++j) acc = fmaf(bn[j], Wem[j * EF + tid], acc);
    } else {
      int cc = tid - EF;
      for (int j = 0; j < HF; ++j) acc = fmaf(bn[j], Wem[(2 * HF + j) * EF + cc], acc);
    }
    wbuf[B_SD + tid] = acc;
  }
  if (tid < NF) {  // bNB
    float acc = bnm[tid];
    for (int j = 0; j < HF; ++j) acc = fmaf(bn[j], Wnm[(HF + j) * NF + tid], acc);
    wbuf[B_NB + tid] = acc;
  }
  if (tid < NC) {  // bnf
    float acc = bfc[tid];
    for (int j = 0; j < HF; ++j) acc = fmaf(bn[j], Wfc[j * NC + tid], acc);
    wbuf[B_NF + tid] = acc;
  }
}

// exclusive scan of cnt[30000] -> off[30001], cursor = copy of off
__global__ void __launch_bounds__(1024) scan_kernel(
    const int* __restrict__ cnt, int* __restrict__ off, int* __restrict__ cursor) {
  __shared__ int part[1024];
  int t = threadIdx.x;
  const int CH = (N_NODES + 1023) / 1024;   // 30
  int base = t * CH;
  int lc[CH];
  int sum = 0;
  for (int i = 0; i < CH; ++i) {
    int idx = base + i;
    lc[i] = (idx < N_NODES) ? cnt[idx] : 0;
    sum += lc[i];
  }
  part[t] = sum;
  __syncthreads();
  for (int ofs = 1; ofs < 1024; ofs <<= 1) {
    int v = (t >= ofs) ? part[t - ofs] : 0;
    __syncthreads();
    part[t] += v;
    __syncthreads();
  }
  int run = (t == 0) ? 0 : part[t - 1];
  for (int i = 0; i < CH; ++i) {
    int idx = base + i;
    if (idx < N_NODES) {
      off[idx] = run;
      cursor[idx] = run;
      run += lc[i];
    }
  }
  if (t == 1023) off[N_NODES] = part[1023];
}

// ---------------------------------------------------------------------------
// scatter (blocks 0..EB-1) + init_proj (blocks EB..EB+NB2-1) fused.
// scatter: counting-sort edges by dst into e_buf0 (+ u16 index copies).
// init:    [Ps|Pd] = x@WSD + bSD ; hpart = x@WnB + bNB  (2 threads/node).
// ---------------------------------------------------------------------------
__global__ void __launch_bounds__(256) scatter_init_kernel(
    const float* __restrict__ edge_feat, const int* __restrict__ src,
    const int* __restrict__ dst, int* __restrict__ cursor,
    unsigned short* __restrict__ src_s, unsigned short* __restrict__ dst_s,
    float* __restrict__ e_buf,
    const float* __restrict__ node_feat, const float* __restrict__ wbuf,
    float* __restrict__ Ps, float* __restrict__ Pd, float* __restrict__ hpart) {
  if (blockIdx.x < EB_GRID) {
    int e = blockIdx.x * 256 + threadIdx.x;
    if (e >= N_EDGES) return;
    int d = dst[e];
    int pos = atomicAdd(&cursor[d], 1);
    src_s[pos] = (unsigned short)src[e];
    dst_s[pos] = (unsigned short)d;
    const float4* ep = (const float4*)(edge_feat + (size_t)e * EF);
    float4* op = (float4*)(e_buf + (size_t)pos * EF);
    op[0] = ep[0]; op[1] = ep[1]; op[2] = ep[2]; op[3] = ep[3];
    return;
  }
  __shared__ float sPRJ[2048];
  __shared__ float sPB[64];
  for (int i = threadIdx.x; i < 2048; i += 256) sPRJ[i] = wbuf[W_SD + i];
  if (threadIdx.x < 64) sPB[threadIdx.x] = wbuf[B_SD + threadIdx.x];
  __syncthreads();
  int gid = (blockIdx.x - EB_GRID) * 256 + threadIdx.x;
  int n = gid >> 1, p = gid & 1;
  if (n >= N_NODES) return;
  float x[NF];
  const float4* xp = (const float4*)(node_feat + (size_t)n * NF);
#pragma unroll
  for (int k4 = 0; k4 < 8; ++k4) {
    float4 v = xp[k4];
    x[4 * k4] = v.x; x[4 * k4 + 1] = v.y; x[4 * k4 + 2] = v.z; x[4 * k4 + 3] = v.w;
  }
  float pr[NF];
  const float* pb = sPB + p * 32;
#pragma unroll
  for (int j = 0; j < NF; ++j) pr[j] = pb[j];
  const float* wbase = sPRJ + p * 1024;
  for (int k = 0; k < NF; ++k) {
    float v = x[k];
    const float4* wr = (const float4*)(wbase + k * NF);
#pragma unroll
    for (int j4 = 0; j4 < 8; ++j4) {
      float4 w = wr[j4];
      pr[4 * j4 + 0] = fmaf(v, w.x, pr[4 * j4 + 0]);
      pr[4 * j4 + 1] = fmaf(v, w.y, pr[4 * j4 + 1]);
      pr[4 * j4 + 2] = fmaf(v, w.z, pr[4 * j4 + 2]);
      pr[4 * j4 + 3] = fmaf(v, w.w, pr[4 * j4 + 3]);
    }
  }
  if (p == 0) {
    float4* a = (float4*)(Ps + (size_t)n * EF);
    a[0] = make_float4(pr[0], pr[1], pr[2], pr[3]);
    a[1] = make_float4(pr[4], pr[5], pr[6], pr[7]);
    a[2] = make_float4(pr[8], pr[9], pr[10], pr[11]);
    a[3] = make_float4(pr[12], pr[13], pr[14], pr[15]);
    float4* b = (float4*)(Pd + (size_t)n * EF);
    b[0] = make_float4(pr[16], pr[17], pr[18], pr[19]);
    b[1] = make_float4(pr[20], pr[21], pr[22], pr[23]);
    b[2] = make_float4(pr[24], pr[25], pr[26], pr[27]);
    b[3] = make_float4(pr[28], pr[29], pr[30], pr[31]);
  } else {
    float4* h = (float4*)(hpart + (size_t)n * NF);
#pragma unroll
    for (int j4 = 0; j4 < 8; ++j4)
      h[j4] = make_float4(pr[4 * j4], pr[4 * j4 + 1], pr[4 * j4 + 2], pr[4 * j4 + 3]);
  }
}

// ---------------------------------------------------------------------------
// fused pass i: edge blocks [0, EB) + node blocks [EB, EB+NB2).
// Both only READ e_src (state i-1); edge writes e_dst (state i) -> no hazard.
// edge_i reads P (written by node_{i-1}); node_i writes P ping-pong partner.
// Bodies identical to the verified 570us 2-way kernels.
// ---------------------------------------------------------------------------
__global__ void __launch_bounds__(256) fused_kernel(
    const float* __restrict__ e_src, float* __restrict__ e_dst,
    const unsigned short* __restrict__ src_s, const unsigned short* __restrict__ dst_s,
    const float* __restrict__ Ps_cur, const float* __restrict__ Pd_cur,
    float* __restrict__ hpart, const int* __restrict__ off,
    const float* __restrict__ wbuf,
    float* __restrict__ Ps_next, float* __restrict__ Pd_next) {
  if (blockIdx.x < EB_GRID) {
    // ---------------- edge body ----------------
    __shared__ float sWC[EF * EF];
    __shared__ float sBC[EF];
    sWC[threadIdx.x] = wbuf[W_COMB + threadIdx.x];
    if (threadIdx.x < EF) sBC[threadIdx.x] = wbuf[B_COMB + threadIdx.x];
    __syncthreads();
    int q = blockIdx.x * 256 + threadIdx.x;
    if (q >= N_EDGES) return;
    int s = src_s[q], d = dst_s[q];

    float e[EF];
    const float4* ebp = (const float4*)(e_src + (size_t)q * EF);
#pragma unroll
    for (int k4 = 0; k4 < 4; ++k4) {
      float4 v = ebp[k4];
      e[4 * k4] = v.x; e[4 * k4 + 1] = v.y; e[4 * k4 + 2] = v.z; e[4 * k4 + 3] = v.w;
    }
    const float4* ps = (const float4*)(Ps_cur + (size_t)s * EF);
    const float4* pd = (const float4*)(Pd_cur + (size_t)d * EF);
    float z[EF];
#pragma unroll
    for (int i4 = 0; i4 < 4; ++i4) {
      float4 a = ps[i4], b = pd[i4];
      z[4 * i4 + 0] = sBC[4 * i4 + 0] + a.x + b.x;
      z[4 * i4 + 1] = sBC[4 * i4 + 1] + a.y + b.y;
      z[4 * i4 + 2] = sBC[4 * i4 + 2] + a.z + b.z;
      z[4 * i4 + 3] = sBC[4 * i4 + 3] + a.w + b.w;
    }
#pragma unroll
    for (int k = 0; k < EF; ++k) {
      float v = e[k];
      const float4* wr = (const float4*)(sWC + k * EF);
#pragma unroll
      for (int i4 = 0; i4 < 4; ++i4) {
        float4 w = wr[i4];
        z[4 * i4 + 0] = fmaf(v, w.x, z[4 * i4 + 0]);
        z[4 * i4 + 1] = fmaf(v, w.y, z[4 * i4 + 1]);
        z[4 * i4 + 2] = fmaf(v, w.z, z[4 * i4 + 2]);
        z[4 * i4 + 3] = fmaf(v, w.w, z[4 * i4 + 3]);
      }
    }
    float4* obp = (float4*)(e_dst + (size_t)q * EF);
#pragma unroll
    for (int i4 = 0; i4 < 4; ++i4)
      obp[i4] = make_float4(sigmoidf_(z[4 * i4]), sigmoidf_(z[4 * i4 + 1]),
                            sigmoidf_(z[4 * i4 + 2]), sigmoidf_(z[4 * i4 + 3]));
    return;
  }
  // ---------------- node body (2 threads/node) ----------------
  __shared__ float sWnc[EF * NF];
  __shared__ float sbvec[NF];
  __shared__ float sPRJ[2048];
  __shared__ float sPB[64];
  for (int i = threadIdx.x; i < 2048; i += 256) sPRJ[i] = wbuf[W_SD + i];
  for (int i = threadIdx.x; i < EF * NF; i += 256) sWnc[i] = wbuf[W_NC + i];
  if (threadIdx.x < 64) sPB[threadIdx.x] = wbuf[B_SD + threadIdx.x];
  if (threadIdx.x < NF) sbvec[threadIdx.x] = wbuf[B_VEC + threadIdx.x];
  __syncthreads();
  int gid = (blockIdx.x - EB_GRID) * 256 + threadIdx.x;
  int n = gid >> 1, p = gid & 1;
  if (n >= N_NODES) return;
  int o0 = off[n], o1 = off[n + 1];

  float s8[8] = {0, 0, 0, 0, 0, 0, 0, 0};
  for (int q = o0; q < o1; ++q) {
    const float4* ep = (const float4*)(e_src + (size_t)q * EF + 8 * p);
    float4 a = ep[0], b = ep[1];
    s8[0] += a.x; s8[1] += a.y; s8[2] += a.z; s8[3] += a.w;
    s8[4] += b.x; s8[5] += b.y; s8[6] += b.z; s8[7] += b.w;
  }

  float z[NF];
  if (p == 0) {
    const float4* hp = (const float4*)(hpart + (size_t)n * NF);
#pragma unroll
    for (int j4 = 0; j4 < 8; ++j4) {
      float4 v = hp[j4];
      z[4 * j4] = v.x; z[4 * j4 + 1] = v.y; z[4 * j4 + 2] = v.z; z[4 * j4 + 3] = v.w;
    }
  } else {
    float dg = (float)(o1 - o0);
#pragma unroll
    for (int j = 0; j < NF; ++j) z[j] = dg * sbvec[j];
  }
#pragma unroll
  for (int k = 0; k < 8; ++k) {
    float v = s8[k];
    const float4* wr = (const float4*)(sWnc + (8 * p + k) * NF);
#pragma unroll
    for (int j4 = 0; j4 < 8; ++j4) {
      float4 w = wr[j4];
      z[4 * j4 + 0] = fmaf(v, w.x, z[4 * j4 + 0]);
      z[4 * j4 + 1] = fmaf(v, w.y, z[4 * j4 + 1]);
      z[4 * j4 + 2] = fmaf(v, w.z, z[4 * j4 + 2]);
      z[4 * j4 + 3] = fmaf(v, w.w, z[4 * j4 + 3]);
    }
  }
#pragma unroll
  for (int j = 0; j < NF; ++j) z[j] += __shfl_xor(z[j], 1, 64);
#pragma unroll
  for (int j = 0; j < NF; ++j) z[j] = sigmoidf_(z[j]);

  float pr[NF];
  const float* pb = sPB + p * 32;
#pragma unroll
  for (int j = 0; j < NF; ++j) pr[j] = pb[j];
  const float* wbase = sPRJ + p * 1024;
  for (int k = 0; k < NF; ++k) {
    float v = z[k];
    const float4* wr = (const float4*)(wbase + k * NF);
#pragma unroll
    for (int j4 = 0; j4 < 8; ++j4) {
      float4 w = wr[j4];
      pr[4 * j4 + 0] = fmaf(v, w.x, pr[4 * j4 + 0]);
      pr[4 * j4 + 1] = fmaf(v, w.y, pr[4 * j4 + 1]);
      pr[4 * j4 + 2] = fmaf(v, w.z, pr[4 * j4 + 2]);
      pr[4 * j4 + 3] = fmaf(v, w.w, pr[4 * j4 + 3]);
    }
  }
  if (p == 0) {
    float4* a = (float4*)(Ps_next + (size_t)n * EF);
    a[0] = make_float4(pr[0], pr[1], pr[2], pr[3]);
    a[1] = make_float4(pr[4], pr[5], pr[6], pr[7]);
    a[2] = make_float4(pr[8], pr[9], pr[10], pr[11]);
    a[3] = make_float4(pr[12], pr[13], pr[14], pr[15]);
    float4* b = (float4*)(Pd_next + (size_t)n * EF);
    b[0] = make_float4(pr[16], pr[17], pr[18], pr[19]);
    b[1] = make_float4(pr[20], pr[21], pr[22], pr[23]);
    b[2] = make_float4(pr[24], pr[25], pr[26], pr[27]);
    b[3] = make_float4(pr[28], pr[29], pr[30], pr[31]);
  } else {
    float4* h = (float4*)(hpart + (size_t)n * NF);
#pragma unroll
    for (int j4 = 0; j4 < 8; ++j4)
      h[j4] = make_float4(pr[4 * j4], pr[4 * j4 + 1], pr[4 * j4 + 2], pr[4 * j4 + 3]);
  }
}

// ---------------------------------------------------------------------------
// final node pass (iter 12): z/sig as above, then out = sig @ Wnf + bnf
// ---------------------------------------------------------------------------
__global__ void __launch_bounds__(256) final_kernel(
    const float* __restrict__ e_buf, const float* __restrict__ hpart,
    const int* __restrict__ off, const float* __restrict__ wbuf,
    float* __restrict__ out) {
  __shared__ float sWnc[EF * NF];
  __shared__ float sbvec[NF];
  __shared__ float sWNF[NF * NC];
  __shared__ float sBNF[NC];
  for (int i = threadIdx.x; i < EF * NF; i += 256) sWnc[i] = wbuf[W_NC + i];
  if (threadIdx.x < NF) sbvec[threadIdx.x] = wbuf[B_VEC + threadIdx.x];
  if (threadIdx.x < NF * NC) sWNF[threadIdx.x] = wbuf[W_NF + threadIdx.x];
  if (threadIdx.x < NC) sBNF[threadIdx.x] = wbuf[B_NF + threadIdx.x];
  __syncthreads();
  int gid = blockIdx.x * 256 + threadIdx.x;
  int n = gid >> 1, p = gid & 1;
  if (n >= N_NODES) return;
  int o0 = off[n], o1 = off[n + 1];

  float s8[8] = {0, 0, 0, 0, 0, 0, 0, 0};
  for (int q = o0; q < o1; ++q) {
    const float4* ep = (const float4*)(e_buf + (size_t)q * EF + 8 * p);
    float4 a = ep[0], b = ep[1];
    s8[0] += a.x; s8[1] += a.y; s8[2] += a.z; s8[3] += a.w;
    s8[4] += b.x; s8[5] += b.y; s8[6] += b.z; s8[7] += b.w;
  }
  float z[NF];
  if (p == 0) {
    const float4* hp = (const float4*)(hpart + (size_t)n * NF);
#pragma unroll
    for (int j4 = 0; j4 < 8; ++j4) {
      float4 v = hp[j4];
      z[4 * j4] = v.x; z[4 * j4 + 1] = v.y; z[4 * j4 + 2] = v.z; z[4 * j4 + 3] = v.w;
    }
  } else {
    float dg = (float)(o1 - o0);
#pragma unroll
    for (int j = 0; j < NF; ++j) z[j] = dg * sbvec[j];
  }
#pragma unroll
  for (int k = 0; k < 8; ++k) {
    float v = s8[k];
    const float4* wr = (const float4*)(sWnc + (8 * p + k) * NF);
#pragma unroll
    for (int j4 = 0; j4 < 8; ++j4) {
      float4 w = wr[j4];
      z[4 * j4 + 0] = fmaf(v, w.x, z[4 * j4 + 0]);
      z[4 * j4 + 1] = fmaf(v, w.y, z[4 * j4 + 1]);
      z[4 * j4 + 2] = fmaf(v, w.z, z[4 * j4 + 2]);
      z[4 * j4 + 3] = fmaf(v, w.w, z[4 * j4 + 3]);
    }
  }
#pragma unroll
  for (int j = 0; j < NF; ++j) z[j] += __shfl_xor(z[j], 1, 64);
#pragma unroll
  for (int j = 0; j < NF; ++j) z[j] = sigmoidf_(z[j]);

  float o[NC];
  float pm = (p == 0) ? 1.0f : 0.0f;
#pragma unroll
  for (int c = 0; c < NC; ++c) o[c] = pm * sBNF[c];
  for (int k = 0; k < 16; ++k) {
    float v = z[16 * p + k];
    const float* wr = sWNF + (16 * p + k) * NC;
#pragma unroll
    for (int c = 0; c < NC; ++c) o[c] = fmaf(v, wr[c], o[c]);
  }
#pragma unroll
  for (int c = 0; c < NC; ++c) o[c] += __shfl_xor(o[c], 1, 64);
  if (p == 0) {
    float4* op = (float4*)(out + (size_t)n * NC);
    op[0] = make_float4(o[0], o[1], o[2], o[3]);
    op[1] = make_float4(o[4], o[5], o[6], o[7]);
  }
}

// ---------------------------------------------------------------------------
extern "C" void kernel_launch(void* const* d_in, const int* in_sizes, int n_in,
                              void* d_out, int out_size, void* d_ws, size_t ws_size,
                              hipStream_t stream) {
  const float* node_feat = (const float*)d_in[0];
  const float* edge_feat = (const float*)d_in[1];
  const int*   src = (const int*)d_in[2];
  const int*   dst = (const int*)d_in[3];
  const float* Wn  = (const float*)d_in[4];
  const float* bn  = (const float*)d_in[5];
  const float* We  = (const float*)d_in[6];
  const float* be  = (const float*)d_in[7];
  const float* Wem = (const float*)d_in[8];
  const float* bem = (const float*)d_in[9];
  const float* Wnm = (const float*)d_in[10];
  const float* bnm = (const float*)d_in[11];
  const float* Wfc = (const float*)d_in[12];
  const float* bfc = (const float*)d_in[13];
  float* out = (float*)d_out;

  float* ws    = (float*)d_ws;
  float* e_b0  = ws;                                   // 3,840,000 f
  float* e_b1  = e_b0 + (size_t)N_EDGES * EF;          // 3,840,000 f
  float* hpart = e_b1 + (size_t)N_EDGES * EF;          //   960,000 f
  float* Ps0   = hpart + (size_t)N_NODES * NF;         //   480,000 f
  float* Pd0   = Ps0 + (size_t)N_NODES * EF;
  float* Ps1   = Pd0 + (size_t)N_NODES * EF;
  float* Pd1   = Ps1 + (size_t)N_NODES * EF;
  float* wbuf  = Pd1 + (size_t)N_NODES * EF;           //     4,096 f
  int* cnt     = (int*)(wbuf + 4096);                  //    30,000 i
  int* off     = cnt + N_NODES;                        //    30,001 i
  int* cursor  = off + N_NODES + 1;                    //    30,000 i
  unsigned short* src_s = (unsigned short*)(cursor + N_NODES);  // 240,000 u16
  unsigned short* dst_s = src_s + N_EDGES;                      // 240,000 u16
  float* PsA[2] = {Ps0, Ps1};
  float* PdA[2] = {Pd0, Pd1};
  float* EbA[2] = {e_b0, e_b1};

  // --- counting sort of edges by dst + weight folding (fused preamble) ---
  hipMemsetAsync(cnt, 0, (size_t)N_NODES * sizeof(int), stream);
  hist_pre_kernel<<<EB_GRID + 1, 256, 0, stream>>>(
      dst, cnt, Wn, bn, We, be, Wem, bem, Wnm, bnm, Wfc, bfc, wbuf);
  scan_kernel<<<1, 1024, 0, stream>>>(cnt, off, cursor);
  scatter_init_kernel<<<EB_GRID + NB2_GRID, 256, 0, stream>>>(
      edge_feat, src, dst, cursor, src_s, dst_s, e_b0,
      node_feat, wbuf, Ps1, Pd1, hpart);

  // 13 reference iterations reduce to 11 fused (node_i || edge_i) + final.
  // node_i and edge_i both read e-state i-1 (e_src); edge writes e_dst
  // (double-buffer removes the in-place WAR hazard, enabling fusion).
  // edge_i reads P[i&1] (from node_{i-1}); node_i writes P[(i+1)&1].
  for (int i = 1; i <= 11; ++i) {
    fused_kernel<<<EB_GRID + NB2_GRID, 256, 0, stream>>>(
        EbA[(i + 1) & 1], EbA[i & 1], src_s, dst_s,
        PsA[i & 1], PdA[i & 1], hpart, off, wbuf,
        PsA[(i + 1) & 1], PdA[(i + 1) & 1]);
  }
  // node pass 12 fused with the output head; e-state 11 lives in EbA[1].
  final_kernel<<<NB2_GRID, 256, 0, stream>>>(EbA[1], hpart, off, wbuf, out);
}